// Round 1
// baseline (1257.799 us; speedup 1.0000x reference)
//
#include <hip/hip_runtime.h>
#include <math.h>

// Problem constants
#define NB 16        // batch
#define CC 512       // channels
#define CQ 64        // query channels
#define HWN 1024     // H*W

typedef float4 f4;

// ---------------------------------------------------------------------------
// Tiled batched GEMM: C[b, m, n] = alpha * sum_k opA(A)[m,k] * opB(B)[k,n] (+ bias[m])
//   A_KM  = true : A stored as (K x M) row-major (direct load)   -> used for S = Q^T K
//   A_KM  = false: A stored as (M x K) row-major (transpose-store into LDS)
//   B_KN  = true : B stored as (K x N) row-major (direct load)
//   B_KN  = false: B stored as (N x K) row-major (transpose-store into LDS)
// Block tile 64x64, 256 threads, 4x4 per thread, K-step 16.
// All tile dims divide evenly for this problem (M in {64,512,1024}, N=1024, K in {64,512,1024}).
// ---------------------------------------------------------------------------
template<bool A_KM, bool B_KN, bool HAS_BIAS>
__global__ __launch_bounds__(256)
void gemm_tile(const float* __restrict__ A, size_t sA, int lda,
               const float* __restrict__ Bm, size_t sB, int ldb,
               const float* __restrict__ bias,
               float* __restrict__ C, size_t sC, int ldc,
               int Ksize, float alpha)
{
    __shared__ float As[16][68];   // [k][m], +4 pad keeps scatter stores ~2-way
    __shared__ float Bs[16][68];   // [k][n]
    const int tid = threadIdx.x;
    const int tr = tid >> 4;       // 0..15 -> owns m rows tr*4..tr*4+3
    const int tc = tid & 15;       // 0..15 -> owns n cols tc*4..tc*4+3
    const int m0 = blockIdx.y << 6;
    const int n0 = blockIdx.x << 6;
    const float* Ab = A  + (size_t)blockIdx.z * sA;
    const float* Bb = Bm + (size_t)blockIdx.z * sB;
    float*       Cb = C  + (size_t)blockIdx.z * sC;

    float acc[4][4] = {};

    for (int k0 = 0; k0 < Ksize; k0 += 16) {
        if (A_KM) {
            const int r = tid >> 4, c4 = (tid & 15) << 2;
            f4 v = *(const f4*)(Ab + (size_t)(k0 + r) * lda + m0 + c4);
            *(f4*)&As[r][c4] = v;
        } else {
            const int r = tid >> 2, c4 = (tid & 3) << 2;
            f4 v = *(const f4*)(Ab + (size_t)(m0 + r) * lda + k0 + c4);
            As[c4 + 0][r] = v.x; As[c4 + 1][r] = v.y;
            As[c4 + 2][r] = v.z; As[c4 + 3][r] = v.w;
        }
        if (B_KN) {
            const int r = tid >> 4, c4 = (tid & 15) << 2;
            f4 v = *(const f4*)(Bb + (size_t)(k0 + r) * ldb + n0 + c4);
            *(f4*)&Bs[r][c4] = v;
        } else {
            const int r = tid >> 2, c4 = (tid & 3) << 2;
            f4 v = *(const f4*)(Bb + (size_t)(n0 + r) * ldb + k0 + c4);
            Bs[c4 + 0][r] = v.x; Bs[c4 + 1][r] = v.y;
            Bs[c4 + 2][r] = v.z; Bs[c4 + 3][r] = v.w;
        }
        __syncthreads();
#pragma unroll
        for (int kk = 0; kk < 16; ++kk) {
            f4 a = *(const f4*)&As[kk][tr << 2];
            f4 b = *(const f4*)&Bs[kk][tc << 2];
            float av[4] = {a.x, a.y, a.z, a.w};
            float bv[4] = {b.x, b.y, b.z, b.w};
#pragma unroll
            for (int i = 0; i < 4; ++i)
#pragma unroll
                for (int j = 0; j < 4; ++j)
                    acc[i][j] = fmaf(av[i], bv[j], acc[i][j]);
        }
        __syncthreads();
    }

#pragma unroll
    for (int i = 0; i < 4; ++i) {
        const int row = m0 + (tr << 2) + i;
        const float bi = HAS_BIAS ? bias[row] : 0.0f;
        f4 o;
        o.x = fmaf(acc[i][0], alpha, bi);
        o.y = fmaf(acc[i][1], alpha, bi);
        o.z = fmaf(acc[i][2], alpha, bi);
        o.w = fmaf(acc[i][3], alpha, bi);
        *(f4*)(Cb + (size_t)row * ldc + n0 + (tc << 2)) = o;
    }
}

// ---------------------------------------------------------------------------
// In-place row softmax over rows of length 1024. One block (256 thr) per row.
// ---------------------------------------------------------------------------
__global__ __launch_bounds__(256)
void softmax_rows(float* __restrict__ S)
{
    float* row = S + ((size_t)blockIdx.x << 10);
    const int t = threadIdx.x;
    f4 v = ((f4*)row)[t];
    float m = fmaxf(fmaxf(v.x, v.y), fmaxf(v.z, v.w));
#pragma unroll
    for (int off = 32; off > 0; off >>= 1) m = fmaxf(m, __shfl_xor(m, off));
    __shared__ float red[4];
    if ((t & 63) == 0) red[t >> 6] = m;
    __syncthreads();
    m = fmaxf(fmaxf(red[0], red[1]), fmaxf(red[2], red[3]));
    __syncthreads();
    v.x = expf(v.x - m); v.y = expf(v.y - m);
    v.z = expf(v.z - m); v.w = expf(v.w - m);
    float s = v.x + v.y + v.z + v.w;
#pragma unroll
    for (int off = 32; off > 0; off >>= 1) s += __shfl_xor(s, off);
    if ((t & 63) == 0) red[t >> 6] = s;
    __syncthreads();
    s = red[0] + red[1] + red[2] + red[3];
    const float inv = 1.0f / s;
    v.x *= inv; v.y *= inv; v.z *= inv; v.w *= inv;
    ((f4*)row)[t] = v;
}

// ---------------------------------------------------------------------------
// BatchNorm statistics: one block per channel o; reduce over (b, hw) = 16384.
// stats[o] = mean, stats[512+o] = rsqrt(var + eps)  (biased var, training mode)
// ---------------------------------------------------------------------------
__global__ __launch_bounds__(256)
void bn_stats(const float* __restrict__ fused, float* __restrict__ stats)
{
    const int o = blockIdx.x, t = threadIdx.x;
    float s = 0.0f, s2 = 0.0f;
    for (int b = 0; b < NB; ++b) {
        f4 v = *(const f4*)(fused + ((size_t)(b * CC + o) << 10) + (t << 2));
        s  += v.x + v.y + v.z + v.w;
        s2 += v.x * v.x + v.y * v.y + v.z * v.z + v.w * v.w;
    }
#pragma unroll
    for (int off = 32; off > 0; off >>= 1) {
        s  += __shfl_xor(s, off);
        s2 += __shfl_xor(s2, off);
    }
    __shared__ float r1[4], r2[4];
    if ((t & 63) == 0) { r1[t >> 6] = s; r2[t >> 6] = s2; }
    __syncthreads();
    if (t == 0) {
        const float S1 = r1[0] + r1[1] + r1[2] + r1[3];
        const float S2 = r2[0] + r2[1] + r2[2] + r2[3];
        const float mean = S1 * (1.0f / 16384.0f);
        const float var  = S2 * (1.0f / 16384.0f) - mean * mean;
        stats[o]       = mean;
        stats[CC + o]  = rsqrtf(var + 1e-5f);
    }
}

// ---------------------------------------------------------------------------
// BN apply + ReLU, elementwise float4.
// ---------------------------------------------------------------------------
__global__ __launch_bounds__(256)
void bn_apply(const float* __restrict__ fused, const float* __restrict__ stats,
              const float* __restrict__ gamma, const float* __restrict__ beta,
              float* __restrict__ out)
{
    const size_t i4 = (size_t)blockIdx.x * 256 + threadIdx.x;  // f4 index
    f4 v = ((const f4*)fused)[i4];
    const int o = (int)((i4 >> 8) & 511);   // float idx = i4*4; channel = (idx>>10)&511
    const float is = stats[CC + o];
    const float g  = gamma[o] * is;
    const float bb = beta[o] - stats[o] * g;
    v.x = fmaxf(fmaf(v.x, g, bb), 0.0f);
    v.y = fmaxf(fmaf(v.y, g, bb), 0.0f);
    v.z = fmaxf(fmaf(v.z, g, bb), 0.0f);
    v.w = fmaxf(fmaf(v.w, g, bb), 0.0f);
    ((f4*)out)[i4] = v;
}

// ---------------------------------------------------------------------------
// Workspace layout (float offsets). Total = 54,525,952 floats = 218,103,808 B.
// ---------------------------------------------------------------------------
static constexpr size_t OFF_VDEP  = 0;                     //  8M floats (B,512,1024)
static constexpr size_t OFF_VRGB  = 8388608;               //  8M
static constexpr size_t OFF_QRGB  = 16777216;              //  1M (B,64,1024)
static constexpr size_t OFF_KDEP  = 17825792;              //  1M
static constexpr size_t OFF_QDEP  = 18874368;              //  1M
static constexpr size_t OFF_KRGB  = 19922944;              //  1M
static constexpr size_t OFF_S     = 20971520;              // 16M (B,1024,1024) scores
static constexpr size_t OFF_FUSED = OFF_S;                 //  8M, reuses S after attn done
static constexpr size_t OFF_STATS = OFF_S + 8388608;       //  1K, upper half of S region
static constexpr size_t OFF_CAT   = 37748736;              // 16M (B,1024,1024) concat attn out

extern "C" void kernel_launch(void* const* d_in, const int* in_sizes, int n_in,
                              void* d_out, int out_size, void* d_ws, size_t ws_size,
                              hipStream_t stream)
{
    const float* rgb    = (const float*)d_in[0];
    const float* depth  = (const float*)d_in[1];
    const float* Wq_rgb = (const float*)d_in[2];
    const float* bq_rgb = (const float*)d_in[3];
    const float* Wk_dep = (const float*)d_in[4];
    const float* bk_dep = (const float*)d_in[5];
    const float* Wv_dep = (const float*)d_in[6];
    const float* bv_dep = (const float*)d_in[7];
    const float* Wq_dep = (const float*)d_in[8];
    const float* bq_dep = (const float*)d_in[9];
    const float* Wk_rgb = (const float*)d_in[10];
    const float* bk_rgb = (const float*)d_in[11];
    const float* Wv_rgb = (const float*)d_in[12];
    const float* bv_rgb = (const float*)d_in[13];
    const float* W_fuse = (const float*)d_in[14];
    const float* gamma  = (const float*)d_in[15];
    const float* beta   = (const float*)d_in[16];
    float* ws  = (float*)d_ws;
    float* out = (float*)d_out;

    const float inv_scale = 0.044194173824159223f;  // 1/sqrt(512) — full C per reference
    const size_t sX = (size_t)CC * HWN;             // batch stride of rgb/depth/V: 524288
    const size_t sQ = (size_t)CQ * HWN;             // 65536
    const size_t sS = (size_t)HWN * HWN;            // 1048576
    const size_t sCat = sS;                         // cat batch stride (1024 ch x 1024)

    dim3 blk(256);
    dim3 gP64(16, 1, NB);    // proj O=64
    dim3 gP512(16, 8, NB);   // proj O=512 / PV / fuse
    dim3 gS(16, 16, NB);     // scores 1024x1024

    // --- 1x1 conv projections: Y[b,o,n] = W[o,c] X[b,c,n] + bias[o] ---
    gemm_tile<false, true, true><<<gP64, blk, 0, stream>>>(
        Wq_rgb, 0, CC, rgb, sX, HWN, bq_rgb, ws + OFF_QRGB, sQ, HWN, CC, 1.0f);
    gemm_tile<false, true, true><<<gP64, blk, 0, stream>>>(
        Wk_dep, 0, CC, depth, sX, HWN, bk_dep, ws + OFF_KDEP, sQ, HWN, CC, 1.0f);
    gemm_tile<false, true, true><<<gP512, blk, 0, stream>>>(
        Wv_dep, 0, CC, depth, sX, HWN, bv_dep, ws + OFF_VDEP, sX, HWN, CC, 1.0f);
    gemm_tile<false, true, true><<<gP64, blk, 0, stream>>>(
        Wq_dep, 0, CC, depth, sX, HWN, bq_dep, ws + OFF_QDEP, sQ, HWN, CC, 1.0f);
    gemm_tile<false, true, true><<<gP64, blk, 0, stream>>>(
        Wk_rgb, 0, CC, rgb, sX, HWN, bk_rgb, ws + OFF_KRGB, sQ, HWN, CC, 1.0f);
    gemm_tile<false, true, true><<<gP512, blk, 0, stream>>>(
        Wv_rgb, 0, CC, rgb, sX, HWN, bv_rgb, ws + OFF_VRGB, sX, HWN, CC, 1.0f);

    // --- Direction 1: rgb attends to depth ---
    // S[b,n,m] = (1/scale) * sum_d Qrgb[b,d,n] Kdep[b,d,m]
    gemm_tile<true, true, false><<<gS, blk, 0, stream>>>(
        ws + OFF_QRGB, sQ, HWN, ws + OFF_KDEP, sQ, HWN, nullptr,
        ws + OFF_S, sS, HWN, CQ, inv_scale);
    softmax_rows<<<NB * HWN, blk, 0, stream>>>(ws + OFF_S);
    // cat[b, c, n] (c in [0,512)) = sum_m Vdep[b,c,m] P[b,n,m]
    gemm_tile<false, false, false><<<gP512, blk, 0, stream>>>(
        ws + OFF_VDEP, sX, HWN, ws + OFF_S, sS, HWN, nullptr,
        ws + OFF_CAT, sCat, HWN, HWN, 1.0f);

    // --- Direction 2: depth attends to rgb ---
    gemm_tile<true, true, false><<<gS, blk, 0, stream>>>(
        ws + OFF_QDEP, sQ, HWN, ws + OFF_KRGB, sQ, HWN, nullptr,
        ws + OFF_S, sS, HWN, CQ, inv_scale);
    softmax_rows<<<NB * HWN, blk, 0, stream>>>(ws + OFF_S);
    gemm_tile<false, false, false><<<gP512, blk, 0, stream>>>(
        ws + OFF_VRGB, sX, HWN, ws + OFF_S, sS, HWN, nullptr,
        ws + OFF_CAT + (size_t)CC * HWN, sCat, HWN, HWN, 1.0f);

    // --- Fuse 1x1 conv over concat (K = 1024), no bias ---
    gemm_tile<false, true, false><<<gP512, blk, 0, stream>>>(
        W_fuse, 0, 2 * CC, ws + OFF_CAT, sCat, HWN, nullptr,
        ws + OFF_FUSED, sX, HWN, 2 * CC, 1.0f);

    // --- BatchNorm (training stats) + ReLU ---
    bn_stats<<<CC, blk, 0, stream>>>(ws + OFF_FUSED, ws + OFF_STATS);
    bn_apply<<<8192, blk, 0, stream>>>(ws + OFF_FUSED, ws + OFF_STATS, gamma, beta, out);
}

// Round 2
// 275.080 us; speedup vs baseline: 4.5725x; 4.5725x over previous
//
#include <hip/hip_runtime.h>
#include <math.h>

#define NB 16
#define CC 512
#define CQ 64
#define HWN 1024

typedef float4 f4;
typedef __bf16 bf16x8 __attribute__((ext_vector_type(8)));
typedef float f32x4 __attribute__((ext_vector_type(4)));
typedef __attribute__((ext_vector_type(8))) unsigned short ushort8v;

__device__ __forceinline__ unsigned short f2bf(float f) {
    unsigned int u = __float_as_uint(f);
    u = (u + 0x7fffu + ((u >> 16) & 1u)) >> 16;
    return (unsigned short)u;
}

// ---------------------------------------------------------------------------
// NT bf16 MFMA GEMM: C[z, m, n] = alpha * (sum_k A[z,m,k]*B[z,n,k] + bias)
// A: M x K row-major bf16 (K contiguous), B: N x K row-major bf16.
// BIAS: 0 none, 1 per-row (bias[m]), 2 per-col (bias[n]).
// Block: 256 threads = 4 waves in 2x2, tile BM x BN, BK=32, reg-staged LDS.
// Requires: M%BM==0, N%BN==0, K%32==0.
// ---------------------------------------------------------------------------
template<int BM, int BN, int BIAS, bool OBF16>
__global__ __launch_bounds__(256)
void mfma_nt(const unsigned short* __restrict__ A, long sA, int lda,
             const unsigned short* __restrict__ B, long sB, int ldb,
             const float* __restrict__ bias,
             void* __restrict__ Cout, long sC, int ldc,
             int Ksize, float alpha)
{
    constexpr int LDK = 40;            // padded LDS row (ushorts): breaks bank aliasing
    constexpr int MF = BM / 32;        // 16x16 frags per wave (M)
    constexpr int NF = BN / 32;        // 16x16 frags per wave (N)
    constexpr int CA = BM / 64;        // 16B chunks per thread for A staging
    constexpr int CB = BN / 64;
    __shared__ unsigned short As[BM * LDK];
    __shared__ unsigned short Bs[BN * LDK];

    const int t    = threadIdx.x;
    const int lane = t & 63;
    const int wid  = t >> 6;
    const int wm   = (wid >> 1) * (BM / 2);
    const int wn   = (wid & 1) * (BN / 2);
    const int m0   = blockIdx.y * BM;
    const int n0   = blockIdx.x * BN;
    const unsigned short* Ab = A + (long)blockIdx.z * sA;
    const unsigned short* Bb = B + (long)blockIdx.z * sB;

    const int sr = t >> 2;             // staging row within 64-row group
    const int sk = (t & 3) << 3;       // staging k offset (ushorts)
    const unsigned short* gA[CA];
    const unsigned short* gB[CB];
#pragma unroll
    for (int c = 0; c < CA; ++c) gA[c] = Ab + (long)(m0 + c * 64 + sr) * lda + sk;
#pragma unroll
    for (int c = 0; c < CB; ++c) gB[c] = Bb + (long)(n0 + c * 64 + sr) * ldb + sk;

    ushort8v ra[CA], rb[CB];
#pragma unroll
    for (int c = 0; c < CA; ++c) ra[c] = *(const ushort8v*)(gA[c]);
#pragma unroll
    for (int c = 0; c < CB; ++c) rb[c] = *(const ushort8v*)(gB[c]);

    f32x4 acc[MF][NF] = {};
    const int l15 = lane & 15;
    const int kh  = (lane >> 4) << 3;  // k-slot: 0,8,16,24

    const int nk = Ksize >> 5;
    for (int it = 0; it < nk; ++it) {
        if (it) __syncthreads();
#pragma unroll
        for (int c = 0; c < CA; ++c)
            *(ushort8v*)&As[(c * 64 + sr) * LDK + sk] = ra[c];
#pragma unroll
        for (int c = 0; c < CB; ++c)
            *(ushort8v*)&Bs[(c * 64 + sr) * LDK + sk] = rb[c];
        __syncthreads();
        if (it + 1 < nk) {
            const int ko = (it + 1) << 5;
#pragma unroll
            for (int c = 0; c < CA; ++c) ra[c] = *(const ushort8v*)(gA[c] + ko);
#pragma unroll
            for (int c = 0; c < CB; ++c) rb[c] = *(const ushort8v*)(gB[c] + ko);
        }
        bf16x8 af[MF], bfv[NF];
#pragma unroll
        for (int i = 0; i < MF; ++i)
            af[i] = *(const bf16x8*)&As[(wm + i * 16 + l15) * LDK + kh];
#pragma unroll
        for (int j = 0; j < NF; ++j)
            bfv[j] = *(const bf16x8*)&Bs[(wn + j * 16 + l15) * LDK + kh];
#pragma unroll
        for (int i = 0; i < MF; ++i)
#pragma unroll
            for (int j = 0; j < NF; ++j)
                acc[i][j] = __builtin_amdgcn_mfma_f32_16x16x32_bf16(af[i], bfv[j], acc[i][j], 0, 0, 0);
        __syncthreads();
    }

    // epilogue: D[m][n], col = lane&15, row = (lane>>4)*4 + r  [m89-verified]
    unsigned short* C16 = (unsigned short*)Cout + (long)blockIdx.z * sC;
    float*          C32 = (float*)Cout + (long)blockIdx.z * sC;
    const int r0 = (lane >> 4) << 2;
#pragma unroll
    for (int i = 0; i < MF; ++i) {
#pragma unroll
        for (int r = 0; r < 4; ++r) {
            const int m = m0 + wm + i * 16 + r0 + r;
            const float brow = (BIAS == 1) ? bias[m] : 0.0f;
#pragma unroll
            for (int j = 0; j < NF; ++j) {
                const int n = n0 + wn + j * 16 + l15;
                const float bb = (BIAS == 2) ? bias[n] : brow;
                const float o = alpha * (acc[i][j][r] + bb);
                if (OBF16) C16[(long)m * ldc + n] = f2bf(o);
                else       C32[(long)m * ldc + n] = o;
            }
        }
    }
}

// ---------------------------------------------------------------------------
// Transpose + fp32->bf16: dst[z][c][r] = bf16(src[z][r][c]); 64x64 tiles.
// ---------------------------------------------------------------------------
__global__ __launch_bounds__(256)
void transpose_cvt(const float* __restrict__ src, unsigned short* __restrict__ dst,
                   int R, int Cn, long sSrc, long sDst)
{
    __shared__ float tile[64][65];
    const int t = threadIdx.x;
    const int c0 = blockIdx.x << 6, r0 = blockIdx.y << 6;
    const float* s = src + (long)blockIdx.z * sSrc;
    unsigned short* d = dst + (long)blockIdx.z * sDst;
    const int lr = t >> 4, lc = (t & 15) << 2;
#pragma unroll
    for (int i = 0; i < 4; ++i) {
        f4 v = *(const f4*)(s + (long)(r0 + lr + i * 16) * Cn + c0 + lc);
        *(f4*)&tile[lr + i * 16][lc] = v;
    }
    __syncthreads();
#pragma unroll
    for (int i = 0; i < 4; ++i) {
        const int crow = lr + i * 16;
        ushort4 o;
        o.x = f2bf(tile[lc + 0][crow]);
        o.y = f2bf(tile[lc + 1][crow]);
        o.z = f2bf(tile[lc + 2][crow]);
        o.w = f2bf(tile[lc + 3][crow]);
        *(ushort4*)&d[(long)(c0 + crow) * R + r0 + lc] = o;
    }
}

// flat fp32 -> bf16
__global__ __launch_bounds__(256)
void cvt_flat(const float* __restrict__ src, unsigned short* __restrict__ dst, int n4)
{
    const int i = blockIdx.x * 256 + threadIdx.x;
    if (i < n4) {
        f4 v = ((const f4*)src)[i];
        ushort4 o;
        o.x = f2bf(v.x); o.y = f2bf(v.y); o.z = f2bf(v.z); o.w = f2bf(v.w);
        ((ushort4*)dst)[i] = o;
    }
}

// bfuse[o] = sum_c Wf[o,c]*bv1[c] + Wf[o,512+c]*bv2[c]
__global__ __launch_bounds__(256)
void bfuse_k(const float* __restrict__ Wf, const float* __restrict__ bv1,
             const float* __restrict__ bv2, float* __restrict__ bfuse)
{
    const int o = blockIdx.x, t = threadIdx.x;
    const float* row = Wf + (long)o * 1024;
    float s = row[t] * bv1[t] + row[512 + t] * bv2[t]
            + row[256 + t] * bv1[256 + t] + row[768 + t] * bv2[256 + t];
#pragma unroll
    for (int off = 32; off; off >>= 1) s += __shfl_xor(s, off);
    __shared__ float r[4];
    if ((t & 63) == 0) r[t >> 6] = s;
    __syncthreads();
    if (t == 0) bfuse[o] = r[0] + r[1] + r[2] + r[3];
}

// row softmax (1024) fp32 in, bf16 out at row stride 2048 with column offset
__global__ __launch_bounds__(256)
void softmax_bf16(const float* __restrict__ S, unsigned short* __restrict__ P, int coloff)
{
    const int blk = blockIdx.x;                 // b*1024 + n
    const float* row = S + ((long)blk << 10);
    unsigned short* prow = P + (long)(blk >> 10) * 2097152
                             + (long)(blk & 1023) * 2048 + coloff;
    const int t = threadIdx.x;
    f4 v = ((const f4*)row)[t];
    float m = fmaxf(fmaxf(v.x, v.y), fmaxf(v.z, v.w));
#pragma unroll
    for (int off = 32; off; off >>= 1) m = fmaxf(m, __shfl_xor(m, off));
    __shared__ float red[4];
    if ((t & 63) == 0) red[t >> 6] = m;
    __syncthreads();
    m = fmaxf(fmaxf(red[0], red[1]), fmaxf(red[2], red[3]));
    __syncthreads();
    v.x = expf(v.x - m); v.y = expf(v.y - m);
    v.z = expf(v.z - m); v.w = expf(v.w - m);
    float s = v.x + v.y + v.z + v.w;
#pragma unroll
    for (int off = 32; off; off >>= 1) s += __shfl_xor(s, off);
    if ((t & 63) == 0) red[t >> 6] = s;
    __syncthreads();
    s = red[0] + red[1] + red[2] + red[3];
    const float inv = 1.0f / s;
    ushort4 o;
    o.x = f2bf(v.x * inv); o.y = f2bf(v.y * inv);
    o.z = f2bf(v.z * inv); o.w = f2bf(v.w * inv);
    *(ushort4*)&prow[t << 2] = o;
}

// BN stats over (b, hw): stats[o]=mean, stats[512+o]=rsqrt(var+eps)
__global__ __launch_bounds__(256)
void bn_stats(const float* __restrict__ fused, float* __restrict__ stats)
{
    const int o = blockIdx.x, t = threadIdx.x;
    float s = 0.0f, s2 = 0.0f;
    for (int b = 0; b < NB; ++b) {
        f4 v = *(const f4*)(fused + ((long)(b * CC + o) << 10) + (t << 2));
        s  += v.x + v.y + v.z + v.w;
        s2 += v.x * v.x + v.y * v.y + v.z * v.z + v.w * v.w;
    }
#pragma unroll
    for (int off = 32; off; off >>= 1) {
        s  += __shfl_xor(s, off);
        s2 += __shfl_xor(s2, off);
    }
    __shared__ float r1[4], r2[4];
    if ((t & 63) == 0) { r1[t >> 6] = s; r2[t >> 6] = s2; }
    __syncthreads();
    if (t == 0) {
        const float S1 = r1[0] + r1[1] + r1[2] + r1[3];
        const float S2 = r2[0] + r2[1] + r2[2] + r2[3];
        const float mean = S1 * (1.0f / 16384.0f);
        const float var  = S2 * (1.0f / 16384.0f) - mean * mean;
        stats[o]      = mean;
        stats[CC + o] = rsqrtf(var + 1e-5f);
    }
}

__global__ __launch_bounds__(256)
void bn_apply(const float* __restrict__ fused, const float* __restrict__ stats,
              const float* __restrict__ gamma, const float* __restrict__ beta,
              float* __restrict__ out)
{
    const long i4 = (long)blockIdx.x * 256 + threadIdx.x;
    f4 v = ((const f4*)fused)[i4];
    const int o = (int)((i4 >> 8) & 511);
    const float is = stats[CC + o];
    const float g  = gamma[o] * is;
    const float bb = beta[o] - stats[o] * g;
    v.x = fmaxf(fmaf(v.x, g, bb), 0.0f);
    v.y = fmaxf(fmaf(v.y, g, bb), 0.0f);
    v.z = fmaxf(fmaf(v.z, g, bb), 0.0f);
    v.w = fmaxf(fmaf(v.w, g, bb), 0.0f);
    ((f4*)out)[i4] = v;
}

// ---------------------------------------------------------------------------
// Workspace layout (BYTE offsets). Total 213,125,120 B (< 218 MB proven).
// ---------------------------------------------------------------------------
static constexpr long B_rgbT  = 0;          // bf16 (16,1024,512)
static constexpr long B_depT  = 16777216;   // bf16
static constexpr long B_WvT1  = 33554432;   // bf16 512x512 (Wv_dep^T)
static constexpr long B_WvT2  = 34078720;
static constexpr long B_Wfb   = 34603008;   // bf16 512x1024 (W_fuse)
static constexpr long B_Wq1   = 35651584;   // bf16 64x512
static constexpr long B_Wk1   = 35717120;
static constexpr long B_Wq2   = 35782656;
static constexpr long B_Wk2   = 35848192;
static constexpr long B_Wc1   = 35913728;   // bf16 512x512 (Wf1@Wv_dep)
static constexpr long B_Wc2   = 36438016;
static constexpr long B_bfu   = 36962304;   // fp32 512
static constexpr long B_Qt1   = 36964352;   // bf16 (16,1024,64)
static constexpr long B_Kt1   = 39061504;
static constexpr long B_Qt2   = 41158656;
static constexpr long B_Kt2   = 43255808;
static constexpr long B_Acat  = 45352960;   // bf16 (16,512,2048)
static constexpr long B_Pcat  = 78907392;   // bf16 (16,1024,2048)
static constexpr long B_S     = 146016256;  // fp32 (16,1024,1024); reused as fused
static constexpr long B_stats = 179570688;  // fp32 1024 (inside upper half of S)

extern "C" void kernel_launch(void* const* d_in, const int* in_sizes, int n_in,
                              void* d_out, int out_size, void* d_ws, size_t ws_size,
                              hipStream_t stream)
{
    const float* rgb    = (const float*)d_in[0];
    const float* depth  = (const float*)d_in[1];
    const float* Wq_rgb = (const float*)d_in[2];
    const float* bq_rgb = (const float*)d_in[3];
    const float* Wk_dep = (const float*)d_in[4];
    const float* bk_dep = (const float*)d_in[5];
    const float* Wv_dep = (const float*)d_in[6];
    const float* bv_dep = (const float*)d_in[7];
    const float* Wq_dep = (const float*)d_in[8];
    const float* bq_dep = (const float*)d_in[9];
    const float* Wk_rgb = (const float*)d_in[10];
    const float* bk_rgb = (const float*)d_in[11];
    const float* Wv_rgb = (const float*)d_in[12];
    const float* bv_rgb = (const float*)d_in[13];
    const float* W_fuse = (const float*)d_in[14];
    const float* gamma  = (const float*)d_in[15];
    const float* beta   = (const float*)d_in[16];
    char* ws = (char*)d_ws;
    float* out = (float*)d_out;

    const float inv_scale = 0.044194173824159223f;  // 1/sqrt(512)
    dim3 blk(256);

    unsigned short* rgbT = (unsigned short*)(ws + B_rgbT);
    unsigned short* depT = (unsigned short*)(ws + B_depT);
    unsigned short* WvT1 = (unsigned short*)(ws + B_WvT1);
    unsigned short* WvT2 = (unsigned short*)(ws + B_WvT2);
    unsigned short* Wfb  = (unsigned short*)(ws + B_Wfb);
    unsigned short* Wq1  = (unsigned short*)(ws + B_Wq1);
    unsigned short* Wk1  = (unsigned short*)(ws + B_Wk1);
    unsigned short* Wq2  = (unsigned short*)(ws + B_Wq2);
    unsigned short* Wk2  = (unsigned short*)(ws + B_Wk2);
    unsigned short* Wc1  = (unsigned short*)(ws + B_Wc1);
    unsigned short* Wc2  = (unsigned short*)(ws + B_Wc2);
    float*          bfu  = (float*)(ws + B_bfu);
    unsigned short* Qt1  = (unsigned short*)(ws + B_Qt1);
    unsigned short* Kt1  = (unsigned short*)(ws + B_Kt1);
    unsigned short* Qt2  = (unsigned short*)(ws + B_Qt2);
    unsigned short* Kt2  = (unsigned short*)(ws + B_Kt2);
    unsigned short* Acat = (unsigned short*)(ws + B_Acat);
    unsigned short* Pcat = (unsigned short*)(ws + B_Pcat);
    float*          Sbuf = (float*)(ws + B_S);
    float*          fused= (float*)(ws + B_S);
    float*          stats= (float*)(ws + B_stats);

    // --- input conversions ---
    transpose_cvt<<<dim3(16, 8, NB), blk, 0, stream>>>(rgb,   rgbT, CC, HWN, 524288, 524288);
    transpose_cvt<<<dim3(16, 8, NB), blk, 0, stream>>>(depth, depT, CC, HWN, 524288, 524288);
    transpose_cvt<<<dim3(8, 8, 1),  blk, 0, stream>>>(Wv_dep, WvT1, CC, CC, 0, 0);
    transpose_cvt<<<dim3(8, 8, 1),  blk, 0, stream>>>(Wv_rgb, WvT2, CC, CC, 0, 0);
    cvt_flat<<<512, blk, 0, stream>>>(W_fuse, Wfb, 131072);
    cvt_flat<<<32,  blk, 0, stream>>>(Wq_rgb, Wq1, 8192);
    cvt_flat<<<32,  blk, 0, stream>>>(Wk_dep, Wk1, 8192);
    cvt_flat<<<32,  blk, 0, stream>>>(Wq_dep, Wq2, 8192);
    cvt_flat<<<32,  blk, 0, stream>>>(Wk_rgb, Wk2, 8192);
    bfuse_k<<<512, blk, 0, stream>>>(W_fuse, bv_dep, bv_rgb, bfu);

    // --- combined weights: Wc1 = Wf[:, :512] @ Wv_dep, Wc2 = Wf[:, 512:] @ Wv_rgb ---
    mfma_nt<128, 128, 0, true><<<dim3(4, 4, 1), blk, 0, stream>>>(
        Wfb, 0, 1024, WvT1, 0, 512, nullptr, Wc1, 0, 512, 512, 1.0f);
    mfma_nt<128, 128, 0, true><<<dim3(4, 4, 1), blk, 0, stream>>>(
        Wfb + 512, 0, 1024, WvT2, 0, 512, nullptr, Wc2, 0, 512, 512, 1.0f);

    // --- Q/K projections: Qt[n,d] = (x^T @ W^T + b) [* inv_scale for Q] ---
    mfma_nt<128, 64, 2, true><<<dim3(1, 8, NB), blk, 0, stream>>>(
        rgbT, 524288, 512, Wq1, 0, 512, bq_rgb, Qt1, 65536, 64, 512, inv_scale);
    mfma_nt<128, 64, 2, true><<<dim3(1, 8, NB), blk, 0, stream>>>(
        depT, 524288, 512, Wk1, 0, 512, bk_dep, Kt1, 65536, 64, 512, 1.0f);
    mfma_nt<128, 64, 2, true><<<dim3(1, 8, NB), blk, 0, stream>>>(
        depT, 524288, 512, Wq2, 0, 512, bq_dep, Qt2, 65536, 64, 512, inv_scale);
    mfma_nt<128, 64, 2, true><<<dim3(1, 8, NB), blk, 0, stream>>>(
        rgbT, 524288, 512, Wk2, 0, 512, bk_rgb, Kt2, 65536, 64, 512, 1.0f);

    // --- A1 = Wc1 @ depth, A2 = Wc2 @ rgb  -> Acat[c, 0:1024 | 1024:2048] ---
    mfma_nt<128, 128, 0, true><<<dim3(8, 4, NB), blk, 0, stream>>>(
        Wc1, 0, 512, depT, 524288, 512, nullptr, Acat, 1048576, 2048, 512, 1.0f);
    mfma_nt<128, 128, 0, true><<<dim3(8, 4, NB), blk, 0, stream>>>(
        Wc2, 0, 512, rgbT, 524288, 512, nullptr, Acat + 1024, 1048576, 2048, 512, 1.0f);

    // --- attention dir 1: S = Qt1 @ Kt1^T (scale folded into Q), softmax -> Pcat[:, :1024]
    mfma_nt<128, 128, 0, false><<<dim3(8, 8, NB), blk, 0, stream>>>(
        Qt1, 65536, 64, Kt1, 65536, 64, nullptr, Sbuf, 1048576, 1024, 64, 1.0f);
    softmax_bf16<<<NB * HWN, blk, 0, stream>>>(Sbuf, Pcat, 0);

    // --- attention dir 2 ---
    mfma_nt<128, 128, 0, false><<<dim3(8, 8, NB), blk, 0, stream>>>(
        Qt2, 65536, 64, Kt2, 65536, 64, nullptr, Sbuf, 1048576, 1024, 64, 1.0f);
    softmax_bf16<<<NB * HWN, blk, 0, stream>>>(Sbuf, Pcat, 1024);

    // --- fused = Acat @ Pcat^T + bfuse  (K = 2048) ---
    mfma_nt<128, 128, 1, false><<<dim3(8, 4, NB), blk, 0, stream>>>(
        Acat, 1048576, 2048, Pcat, 2097152, 2048, bfu, fused, 524288, 1024, 2048, 1.0f);

    // --- BN (training stats) + ReLU ---
    bn_stats<<<CC, blk, 0, stream>>>(fused, stats);
    bn_apply<<<8192, blk, 0, stream>>>(fused, stats, gamma, beta, out);
}

// Round 3
// 271.059 us; speedup vs baseline: 4.6403x; 1.0148x over previous
//
#include <hip/hip_runtime.h>
#include <math.h>

#define NB 16
#define CC 512
#define CQ 64
#define HWN 1024

typedef float4 f4;
typedef __bf16 bf16x8 __attribute__((ext_vector_type(8)));
typedef float f32x4 __attribute__((ext_vector_type(4)));
typedef __attribute__((ext_vector_type(8))) unsigned short ushort8v;

__device__ __forceinline__ unsigned short f2bf(float f) {
    unsigned int u = __float_as_uint(f);
    u = (u + 0x7fffu + ((u >> 16) & 1u)) >> 16;
    return (unsigned short)u;
}
__device__ __forceinline__ float bf2f(unsigned short u) {
    return __uint_as_float(((unsigned int)u) << 16);
}

// async global->LDS, 16B per lane. LDS dest = wave-uniform base + lane*16.
__device__ __forceinline__ void gload16(const unsigned short* g, unsigned short* l) {
    __builtin_amdgcn_global_load_lds(
        (const __attribute__((address_space(1))) unsigned int*)g,
        (__attribute__((address_space(3))) unsigned int*)l,
        16, 0, 0);
}

// ---------------------------------------------------------------------------
// NT bf16 MFMA GEMM, m97-structure: C[z,m,n] = alpha*(sum_k A[z,m,k]*B[z,n,k]+bias)
// A: MxK row-major bf16, B: NxK row-major bf16 (both K-contiguous).
// Linear LDS [rows][32] (64 B rows), staged via global_load_lds dwordx4.
// Lane l of a wave covers seg row (l>>2), 16B chunk (l&3)  ->  base + l*16. ✓
// BIAS: 0 none, 1 per-row bias[m], 2 per-col bias[n].
// ---------------------------------------------------------------------------
template<int BM, int BN, int BIAS, bool OBF16>
__global__ __launch_bounds__(256)
void mfma_nt2(const unsigned short* __restrict__ A, long sA, int lda,
              const unsigned short* __restrict__ B, long sB, int ldb,
              const float* __restrict__ bias,
              void* __restrict__ Cout, long sC, int ldc,
              int Ksize, float alpha)
{
    constexpr int MF = BM / 32;        // frags per wave (M), 2x2 wave grid
    constexpr int NF = BN / 32;
    constexpr int CA = BM / 64;        // gload calls per wave for A
    constexpr int CB = BN / 64;
    __shared__ unsigned short As[BM * 32];
    __shared__ unsigned short Bs[BN * 32];

    const int t = threadIdx.x, lane = t & 63, wid = t >> 6;
    const int wm = (wid >> 1) * (BM / 2);
    const int wn = (wid & 1) * (BN / 2);
    const int m0 = blockIdx.y * BM;
    const int n0 = blockIdx.x * BN;
    const unsigned short* Ab = A + (long)blockIdx.z * sA;
    const unsigned short* Bb = B + (long)blockIdx.z * sB;

    const int srow = lane >> 2, scol = (lane & 3) << 3;   // within 16-row seg
    const unsigned short* gA[CA]; unsigned short* lA[CA];
    const unsigned short* gB[CB]; unsigned short* lB[CB];
#pragma unroll
    for (int c = 0; c < CA; ++c) {
        const int seg = wid + 4 * c;
        gA[c] = Ab + (long)(m0 + seg * 16 + srow) * lda + scol;
        lA[c] = &As[seg * 512];
    }
#pragma unroll
    for (int c = 0; c < CB; ++c) {
        const int seg = wid + 4 * c;
        gB[c] = Bb + (long)(n0 + seg * 16 + srow) * ldb + scol;
        lB[c] = &Bs[seg * 512];
    }

    f32x4 acc[MF][NF] = {};
    const int l15 = lane & 15;
    const int kh  = (lane >> 4) << 3;

    for (int k0 = 0; k0 < Ksize; k0 += 32) {
#pragma unroll
        for (int c = 0; c < CA; ++c) gload16(gA[c] + k0, lA[c]);
#pragma unroll
        for (int c = 0; c < CB; ++c) gload16(gB[c] + k0, lB[c]);
        __syncthreads();                       // drains vmcnt before barrier
        bf16x8 af[MF], bfv[NF];
#pragma unroll
        for (int i = 0; i < MF; ++i)
            af[i] = *(const bf16x8*)&As[(wm + i * 16 + l15) * 32 + kh];
#pragma unroll
        for (int j = 0; j < NF; ++j)
            bfv[j] = *(const bf16x8*)&Bs[(wn + j * 16 + l15) * 32 + kh];
#pragma unroll
        for (int i = 0; i < MF; ++i)
#pragma unroll
            for (int j = 0; j < NF; ++j)
                acc[i][j] = __builtin_amdgcn_mfma_f32_16x16x32_bf16(af[i], bfv[j], acc[i][j], 0, 0, 0);
        __syncthreads();
    }

    unsigned short* C16 = (unsigned short*)Cout + (long)blockIdx.z * sC;
    float*          C32 = (float*)Cout + (long)blockIdx.z * sC;
    const int r0 = (lane >> 4) << 2;
#pragma unroll
    for (int i = 0; i < MF; ++i) {
#pragma unroll
        for (int r = 0; r < 4; ++r) {
            const int m = m0 + wm + i * 16 + r0 + r;
            const float brow = (BIAS == 1) ? bias[m] : 0.0f;
#pragma unroll
            for (int j = 0; j < NF; ++j) {
                const int n = n0 + wn + j * 16 + l15;
                const float bb = (BIAS == 2) ? bias[n] : brow;
                const float o = alpha * (acc[i][j][r] + bb);
                if (OBF16) C16[(long)m * ldc + n] = f2bf(o);
                else       C32[(long)m * ldc + n] = o;
            }
        }
    }
}

// ---------------------------------------------------------------------------
// Fused QK^T + softmax -> Pcat bf16. Block = 32 q-rows x full 1024 kv, one
// (batch, dir). S kept raw-bf16 in 64KB LDS (logits |s|<~0.5 -> safe).
// Waves: (w&1) = 16-row m-frag, (w>>1) = 512-col half. K read direct from
// global (L2-resident, 128 KB/batch). Phase 2: per-wave row softmax.
// ---------------------------------------------------------------------------
__global__ __launch_bounds__(256)
void attn_fused(const unsigned short* __restrict__ Qt1, const unsigned short* __restrict__ Kt1,
                const unsigned short* __restrict__ Qt2, const unsigned short* __restrict__ Kt2,
                unsigned short* __restrict__ Pcat)
{
    __shared__ unsigned short Ss[32][1024];
    const int t = threadIdx.x, lane = t & 63, w = t >> 6;
    const int bx = blockIdx.x, b = blockIdx.y, dir = blockIdx.z;
    const unsigned short* Q = (dir ? Qt2 : Qt1) + (long)b * 65536;
    const unsigned short* K = (dir ? Kt2 : Kt1) + (long)b * 65536;
    const int l15 = lane & 15, kg = (lane >> 4) << 3;

    const long mrow = bx * 32 + (w & 1) * 16 + l15;   // A-frag row = lane&15
    bf16x8 aq0 = *(const bf16x8*)&Q[mrow * 64 + kg];
    bf16x8 aq1 = *(const bf16x8*)&Q[mrow * 64 + 32 + kg];

    const int colbase = (w >> 1) * 512;
    const int rbase = (w & 1) * 16 + (lane >> 4) * 4;  // C rows: (lane>>4)*4+r
    for (int c = 0; c < 4; ++c) {
        const int n0 = colbase + c * 128;
        bf16x8 bk0[8], bk1[8];
#pragma unroll
        for (int j = 0; j < 8; ++j) {
            const long krow = n0 + j * 16 + l15;
            bk0[j] = *(const bf16x8*)&K[krow * 64 + kg];
            bk1[j] = *(const bf16x8*)&K[krow * 64 + 32 + kg];
        }
#pragma unroll
        for (int j = 0; j < 8; ++j) {
            f32x4 a = {0.f, 0.f, 0.f, 0.f};
            a = __builtin_amdgcn_mfma_f32_16x16x32_bf16(aq0, bk0[j], a, 0, 0, 0);
            a = __builtin_amdgcn_mfma_f32_16x16x32_bf16(aq1, bk1[j], a, 0, 0, 0);
            const int col = n0 + j * 16 + l15;
#pragma unroll
            for (int r = 0; r < 4; ++r)
                Ss[rbase + r][col] = f2bf(a[r]);
        }
    }
    __syncthreads();

    // phase 2: rows w*8 .. w*8+7, all 64 lanes per row
    for (int rr = 0; rr < 8; ++rr) {
        const int R = w * 8 + rr;
        ushort8v u0 = *(const ushort8v*)&Ss[R][lane * 8];
        ushort8v u1 = *(const ushort8v*)&Ss[R][512 + lane * 8];
        float v[16];
#pragma unroll
        for (int i = 0; i < 8; ++i) { v[i] = bf2f(u0[i]); v[8 + i] = bf2f(u1[i]); }
        float m = v[0];
#pragma unroll
        for (int i = 1; i < 16; ++i) m = fmaxf(m, v[i]);
#pragma unroll
        for (int off = 32; off; off >>= 1) m = fmaxf(m, __shfl_xor(m, off));
        float s = 0.0f;
#pragma unroll
        for (int i = 0; i < 16; ++i) { v[i] = __expf(v[i] - m); s += v[i]; }
#pragma unroll
        for (int off = 32; off; off >>= 1) s += __shfl_xor(s, off);
        const float inv = 1.0f / s;
        ushort8v o0, o1;
#pragma unroll
        for (int i = 0; i < 8; ++i) { o0[i] = f2bf(v[i] * inv); o1[i] = f2bf(v[8 + i] * inv); }
        unsigned short* dst = Pcat + ((long)(b * 1024 + bx * 32 + R)) * 2048 + dir * 1024 + lane * 8;
        *(ushort8v*)dst = o0;
        *(ushort8v*)(dst + 512) = o1;
    }
}

// ---------------------------------------------------------------------------
// Transpose + fp32->bf16: dst[z][c][r] = bf16(src[z][r][c]); 64x64 tiles.
// ---------------------------------------------------------------------------
__global__ __launch_bounds__(256)
void transpose_cvt(const float* __restrict__ src, unsigned short* __restrict__ dst,
                   int R, int Cn, long sSrc, long sDst)
{
    __shared__ float tile[64][65];
    const int t = threadIdx.x;
    const int c0 = blockIdx.x << 6, r0 = blockIdx.y << 6;
    const float* s = src + (long)blockIdx.z * sSrc;
    unsigned short* d = dst + (long)blockIdx.z * sDst;
    const int lr = t >> 4, lc = (t & 15) << 2;
#pragma unroll
    for (int i = 0; i < 4; ++i) {
        f4 v = *(const f4*)(s + (long)(r0 + lr + i * 16) * Cn + c0 + lc);
        *(f4*)&tile[lr + i * 16][lc] = v;
    }
    __syncthreads();
#pragma unroll
    for (int i = 0; i < 4; ++i) {
        const int crow = lr + i * 16;
        ushort4 o;
        o.x = f2bf(tile[lc + 0][crow]);
        o.y = f2bf(tile[lc + 1][crow]);
        o.z = f2bf(tile[lc + 2][crow]);
        o.w = f2bf(tile[lc + 3][crow]);
        *(ushort4*)&d[(long)(c0 + crow) * R + r0 + lc] = o;
    }
}

__global__ __launch_bounds__(256)
void cvt_flat(const float* __restrict__ src, unsigned short* __restrict__ dst, int n4)
{
    const int i = blockIdx.x * 256 + threadIdx.x;
    if (i < n4) {
        f4 v = ((const f4*)src)[i];
        ushort4 o;
        o.x = f2bf(v.x); o.y = f2bf(v.y); o.z = f2bf(v.z); o.w = f2bf(v.w);
        ((ushort4*)dst)[i] = o;
    }
}

__global__ __launch_bounds__(256)
void bfuse_k(const float* __restrict__ Wf, const float* __restrict__ bv1,
             const float* __restrict__ bv2, float* __restrict__ bfuse)
{
    const int o = blockIdx.x, t = threadIdx.x;
    const float* row = Wf + (long)o * 1024;
    float s = row[t] * bv1[t] + row[512 + t] * bv2[t]
            + row[256 + t] * bv1[256 + t] + row[768 + t] * bv2[256 + t];
#pragma unroll
    for (int off = 32; off; off >>= 1) s += __shfl_xor(s, off);
    __shared__ float r[4];
    if ((t & 63) == 0) r[t >> 6] = s;
    __syncthreads();
    if (t == 0) bfuse[o] = r[0] + r[1] + r[2] + r[3];
}

__global__ __launch_bounds__(256)
void bn_stats(const float* __restrict__ fused, float* __restrict__ stats)
{
    const int o = blockIdx.x, t = threadIdx.x;
    float s = 0.0f, s2 = 0.0f;
    for (int b = 0; b < NB; ++b) {
        f4 v = *(const f4*)(fused + ((long)(b * CC + o) << 10) + (t << 2));
        s  += v.x + v.y + v.z + v.w;
        s2 += v.x * v.x + v.y * v.y + v.z * v.z + v.w * v.w;
    }
#pragma unroll
    for (int off = 32; off; off >>= 1) {
        s  += __shfl_xor(s, off);
        s2 += __shfl_xor(s2, off);
    }
    __shared__ float r1[4], r2[4];
    if ((t & 63) == 0) { r1[t >> 6] = s; r2[t >> 6] = s2; }
    __syncthreads();
    if (t == 0) {
        const float S1 = r1[0] + r1[1] + r1[2] + r1[3];
        const float S2 = r2[0] + r2[1] + r2[2] + r2[3];
        const float mean = S1 * (1.0f / 16384.0f);
        const float var  = S2 * (1.0f / 16384.0f) - mean * mean;
        stats[o]      = mean;
        stats[CC + o] = rsqrtf(var + 1e-5f);
    }
}

__global__ __launch_bounds__(256)
void bn_apply(const float* __restrict__ fused, const float* __restrict__ stats,
              const float* __restrict__ gamma, const float* __restrict__ beta,
              float* __restrict__ out)
{
    const long i4 = (long)blockIdx.x * 256 + threadIdx.x;
    f4 v = ((const f4*)fused)[i4];
    const int o = (int)((i4 >> 8) & 511);
    const float is = stats[CC + o];
    const float g  = gamma[o] * is;
    const float bb = beta[o] - stats[o] * g;
    v.x = fmaxf(fmaf(v.x, g, bb), 0.0f);
    v.y = fmaxf(fmaf(v.y, g, bb), 0.0f);
    v.z = fmaxf(fmaf(v.z, g, bb), 0.0f);
    v.w = fmaxf(fmaf(v.w, g, bb), 0.0f);
    ((f4*)out)[i4] = v;
}

// ---------------------------------------------------------------------------
// Workspace layout (BYTE offsets), total < 218 MB (proven available).
// ---------------------------------------------------------------------------
static constexpr long B_rgbT  = 0;          // bf16 (16,1024,512)
static constexpr long B_depT  = 16777216;
static constexpr long B_WvT1  = 33554432;   // bf16 512x512
static constexpr long B_WvT2  = 34078720;
static constexpr long B_Wfb   = 34603008;   // bf16 512x1024
static constexpr long B_Wq1   = 35651584;   // bf16 64x512
static constexpr long B_Wk1   = 35717120;
static constexpr long B_Wq2   = 35782656;
static constexpr long B_Wk2   = 35848192;
static constexpr long B_Wc1   = 35913728;   // bf16 512x512
static constexpr long B_Wc2   = 36438016;
static constexpr long B_bfu   = 36962304;   // fp32 512
static constexpr long B_Qt1   = 36964352;   // bf16 (16,1024,64)
static constexpr long B_Kt1   = 39061504;
static constexpr long B_Qt2   = 41158656;
static constexpr long B_Kt2   = 43255808;
static constexpr long B_Acat  = 45352960;   // bf16 (16,512,2048)
static constexpr long B_Pcat  = 78907392;   // bf16 (16,1024,2048)
static constexpr long B_S     = 146016256;  // fp32 (16,512,1024) = fused
static constexpr long B_stats = 179570688;  // fp32 1024

extern "C" void kernel_launch(void* const* d_in, const int* in_sizes, int n_in,
                              void* d_out, int out_size, void* d_ws, size_t ws_size,
                              hipStream_t stream)
{
    const float* rgb    = (const float*)d_in[0];
    const float* depth  = (const float*)d_in[1];
    const float* Wq_rgb = (const float*)d_in[2];
    const float* bq_rgb = (const float*)d_in[3];
    const float* Wk_dep = (const float*)d_in[4];
    const float* bk_dep = (const float*)d_in[5];
    const float* Wv_dep = (const float*)d_in[6];
    const float* bv_dep = (const float*)d_in[7];
    const float* Wq_dep = (const float*)d_in[8];
    const float* bq_dep = (const float*)d_in[9];
    const float* Wk_rgb = (const float*)d_in[10];
    const float* bk_rgb = (const float*)d_in[11];
    const float* Wv_rgb = (const float*)d_in[12];
    const float* bv_rgb = (const float*)d_in[13];
    const float* W_fuse = (const float*)d_in[14];
    const float* gamma  = (const float*)d_in[15];
    const float* beta   = (const float*)d_in[16];
    char* ws = (char*)d_ws;
    float* out = (float*)d_out;

    const float inv_scale = 0.044194173824159223f;  // 1/sqrt(512)
    dim3 blk(256);

    unsigned short* rgbT = (unsigned short*)(ws + B_rgbT);
    unsigned short* depT = (unsigned short*)(ws + B_depT);
    unsigned short* WvT1 = (unsigned short*)(ws + B_WvT1);
    unsigned short* WvT2 = (unsigned short*)(ws + B_WvT2);
    unsigned short* Wfb  = (unsigned short*)(ws + B_Wfb);
    unsigned short* Wq1  = (unsigned short*)(ws + B_Wq1);
    unsigned short* Wk1  = (unsigned short*)(ws + B_Wk1);
    unsigned short* Wq2  = (unsigned short*)(ws + B_Wq2);
    unsigned short* Wk2  = (unsigned short*)(ws + B_Wk2);
    unsigned short* Wc1  = (unsigned short*)(ws + B_Wc1);
    unsigned short* Wc2  = (unsigned short*)(ws + B_Wc2);
    float*          bfu  = (float*)(ws + B_bfu);
    unsigned short* Qt1  = (unsigned short*)(ws + B_Qt1);
    unsigned short* Kt1  = (unsigned short*)(ws + B_Kt1);
    unsigned short* Qt2  = (unsigned short*)(ws + B_Qt2);
    unsigned short* Kt2  = (unsigned short*)(ws + B_Kt2);
    unsigned short* Acat = (unsigned short*)(ws + B_Acat);
    unsigned short* Pcat = (unsigned short*)(ws + B_Pcat);
    float*          fused= (float*)(ws + B_S);
    float*          stats= (float*)(ws + B_stats);

    // --- input conversions ---
    transpose_cvt<<<dim3(16, 8, NB), blk, 0, stream>>>(rgb,   rgbT, CC, HWN, 524288, 524288);
    transpose_cvt<<<dim3(16, 8, NB), blk, 0, stream>>>(depth, depT, CC, HWN, 524288, 524288);
    transpose_cvt<<<dim3(8, 8, 1),  blk, 0, stream>>>(Wv_dep, WvT1, CC, CC, 0, 0);
    transpose_cvt<<<dim3(8, 8, 1),  blk, 0, stream>>>(Wv_rgb, WvT2, CC, CC, 0, 0);
    cvt_flat<<<512, blk, 0, stream>>>(W_fuse, Wfb, 131072);
    cvt_flat<<<32,  blk, 0, stream>>>(Wq_rgb, Wq1, 8192);
    cvt_flat<<<32,  blk, 0, stream>>>(Wk_dep, Wk1, 8192);
    cvt_flat<<<32,  blk, 0, stream>>>(Wq_dep, Wq2, 8192);
    cvt_flat<<<32,  blk, 0, stream>>>(Wk_rgb, Wk2, 8192);
    bfuse_k<<<512, blk, 0, stream>>>(W_fuse, bv_dep, bv_rgb, bfu);

    // --- combined weights: Wc1 = Wf[:, :512] @ Wv_dep, Wc2 = Wf[:, 512:] @ Wv_rgb ---
    mfma_nt2<128, 128, 0, true><<<dim3(4, 4, 1), blk, 0, stream>>>(
        Wfb, 0, 1024, WvT1, 0, 512, nullptr, Wc1, 0, 512, 512, 1.0f);
    mfma_nt2<128, 128, 0, true><<<dim3(4, 4, 1), blk, 0, stream>>>(
        Wfb + 512, 0, 1024, WvT2, 0, 512, nullptr, Wc2, 0, 512, 512, 1.0f);

    // --- Q/K projections (scale folded into Q) ---
    mfma_nt2<128, 64, 2, true><<<dim3(1, 8, NB), blk, 0, stream>>>(
        rgbT, 524288, 512, Wq1, 0, 512, bq_rgb, Qt1, 65536, 64, 512, inv_scale);
    mfma_nt2<128, 64, 2, true><<<dim3(1, 8, NB), blk, 0, stream>>>(
        depT, 524288, 512, Wk1, 0, 512, bk_dep, Kt1, 65536, 64, 512, 1.0f);
    mfma_nt2<128, 64, 2, true><<<dim3(1, 8, NB), blk, 0, stream>>>(
        depT, 524288, 512, Wq2, 0, 512, bq_dep, Qt2, 65536, 64, 512, inv_scale);
    mfma_nt2<128, 64, 2, true><<<dim3(1, 8, NB), blk, 0, stream>>>(
        rgbT, 524288, 512, Wk2, 0, 512, bk_rgb, Kt2, 65536, 64, 512, 1.0f);

    // --- A1 = Wc1 @ depth, A2 = Wc2 @ rgb -> Acat ---
    mfma_nt2<128, 128, 0, true><<<dim3(8, 4, NB), blk, 0, stream>>>(
        Wc1, 0, 512, depT, 524288, 512, nullptr, Acat, 1048576, 2048, 512, 1.0f);
    mfma_nt2<128, 128, 0, true><<<dim3(8, 4, NB), blk, 0, stream>>>(
        Wc2, 0, 512, rgbT, 524288, 512, nullptr, Acat + 1024, 1048576, 2048, 512, 1.0f);

    // --- fused attention: QK^T + softmax -> Pcat (both directions) ---
    attn_fused<<<dim3(32, NB, 2), blk, 0, stream>>>(Qt1, Kt1, Qt2, Kt2, Pcat);

    // --- fused = Acat @ Pcat^T + bfuse (K = 2048) ---
    mfma_nt2<128, 128, 1, false><<<dim3(8, 4, NB), blk, 0, stream>>>(
        Acat, 1048576, 2048, Pcat, 2097152, 2048, bfu, fused, 524288, 1024, 2048, 1.0f);

    // --- BN (training stats) + ReLU ---
    bn_stats<<<CC, blk, 0, stream>>>(fused, stats);
    bn_apply<<<8192, blk, 0, stream>>>(fused, stats, gamma, beta, out);
}

// Round 5
// 187.856 us; speedup vs baseline: 6.6955x; 1.4429x over previous
//
#include <hip/hip_runtime.h>
#include <math.h>

#define NB 16
#define CC 512
#define CQ 64
#define HWN 1024

typedef float4 f4;
typedef __bf16 bf16x8 __attribute__((ext_vector_type(8)));
typedef float f32x4 __attribute__((ext_vector_type(4)));
typedef __attribute__((ext_vector_type(8))) unsigned short ushort8v;

__device__ __forceinline__ unsigned short f2bf(float f) {
    unsigned int u = __float_as_uint(f);
    u = (u + 0x7fffu + ((u >> 16) & 1u)) >> 16;
    return (unsigned short)u;
}
__device__ __forceinline__ float bf2f(unsigned short u) {
    return __uint_as_float(((unsigned int)u) << 16);
}

__device__ __forceinline__ void gload16(const unsigned short* g, unsigned short* l) {
    __builtin_amdgcn_global_load_lds(
        (const __attribute__((address_space(1))) unsigned int*)g,
        (__attribute__((address_space(3))) unsigned int*)l,
        16, 0, 0);
}

// ---------------------------------------------------------------------------
// Generalized NT bf16 MFMA GEMM, 2-phase double-buffered (T3 minimum recipe):
//   C[z,m,n] = alpha * (sum_k A[z,m,k]*B[z,n,k] + bias)
// Batch decomposition: zlo = z & (2^ZSH-1), zhi = z >> ZSH;
//   Ab = A + zlo*sAlo + zhi*sAhi   (elements), same for B, C; bias + zhi*sBiasHi.
// BK=64, LDS rows 128 B, slot-XOR swizzle (s^=(row&7)) -> conflict-free frag
// reads (2 lanes/bank). Swizzle applied on the GLOBAL source column (rule #21:
// linear LDS dest via global_load_lds + same involution on the read side).
// K-loop: STAGE(t+1 -> other buf) issued BEFORE ds_read+MFMA of t; ONE
// barrier per K-step drains vmcnt after MFMA has covered the latency.
// BIAS: 0 none, 1 per-row bias[m], 2 per-col bias[n].
// Grid must satisfy nwg % 8 == 0 (bijective XCD-chunked swizzle).
// ---------------------------------------------------------------------------
template<int BM, int BN, int BIAS, bool OBF16, int ZSH>
__global__ __launch_bounds__(256)
void mfma_g(const unsigned short* __restrict__ A, long sAlo, long sAhi, int lda,
            const unsigned short* __restrict__ B, long sBlo, long sBhi, int ldb,
            const float* __restrict__ bias, long sBiasHi,
            void* __restrict__ Cout, long sClo, long sChi, int ldc,
            int Ksize, float alpha)
{
    constexpr int MF = BM / 32;            // 16-row frags per wave (M)
    constexpr int NF = BN / 32;
    constexpr int CA = BM / 32;            // gloads per wave for A (BM/8 segs / 4 waves)
    constexpr int CB = BN / 32;
    __shared__ unsigned short As[2][BM * 64];
    __shared__ unsigned short Bs[2][BN * 64];

    // XCD-chunked bijective swizzle: physical p -> logical (p%8)*(n/8)+p/8
    const int gx = gridDim.x, gy = gridDim.y;
    int f = blockIdx.x + gx * (blockIdx.y + gy * blockIdx.z);
    const int nwg = gx * gy * gridDim.z;
    f = (f & 7) * (nwg >> 3) + (f >> 3);
    const int bx = f % gx; const int t2 = f / gx;
    const int by = t2 % gy; const int bz = t2 / gy;

    const int zlo = ZSH ? (bz & ((1 << ZSH) - 1)) : 0;
    const int zhi = bz >> ZSH;

    const int t = threadIdx.x, lane = t & 63, wid = t >> 6;
    const int wm = (wid >> 1) * (BM / 2), wn = (wid & 1) * (BN / 2);
    const int m0 = by * BM, n0 = bx * BN;
    const unsigned short* Ab = A + (long)zlo * sAlo + (long)zhi * sAhi;
    const unsigned short* Bb = B + (long)zlo * sBlo + (long)zhi * sBhi;

    // staging: each gload = 8 rows x 128B; source col pre-swizzled (involution)
    const int srow = lane >> 3;                               // 0..7
    const int scol = ((lane & 7) ^ srow) << 3;                // swizzled k-slot
    const unsigned short* gA[CA]; const unsigned short* gB[CB];
    unsigned short* lA[CA]; unsigned short* lB[CB];
#pragma unroll
    for (int c = 0; c < CA; ++c) {
        const int seg = wid + 4 * c;
        gA[c] = Ab + (long)(m0 + seg * 8 + srow) * lda + scol;
        lA[c] = &As[0][seg * 512];
    }
#pragma unroll
    for (int c = 0; c < CB; ++c) {
        const int seg = wid + 4 * c;
        gB[c] = Bb + (long)(n0 + seg * 8 + srow) * ldb + scol;
        lB[c] = &Bs[0][seg * 512];
    }

    f32x4 acc[MF][NF] = {};
    const int l15 = lane & 15, slot = lane >> 4;              // slot 0..3

    // prologue: stage tile 0 into buf 0, drain
#pragma unroll
    for (int c = 0; c < CA; ++c) gload16(gA[c], lA[c]);
#pragma unroll
    for (int c = 0; c < CB; ++c) gload16(gB[c], lB[c]);
    __syncthreads();

    const int nt = Ksize >> 6;
    int cur = 0;
    for (int tt = 0; tt < nt; ++tt) {
        if (tt + 1 < nt) {                                    // issue next-tile loads FIRST
            const int ko = (tt + 1) << 6;
            const int nb = cur ^ 1;
#pragma unroll
            for (int c = 0; c < CA; ++c) gload16(gA[c] + ko, lA[c] + nb * (BM * 64));
#pragma unroll
            for (int c = 0; c < CB; ++c) gload16(gB[c] + ko, lB[c] + nb * (BN * 64));
        }
        bf16x8 alo[MF], ahi[MF], blo[NF], bhi[NF];
#pragma unroll
        for (int i = 0; i < MF; ++i) {
            const int r = wm + i * 16 + l15;
            alo[i] = *(const bf16x8*)&As[cur][r * 64 + ((slot ^ (r & 7)) << 3)];
            ahi[i] = *(const bf16x8*)&As[cur][r * 64 + (((slot + 4) ^ (r & 7)) << 3)];
        }
#pragma unroll
        for (int j = 0; j < NF; ++j) {
            const int r = wn + j * 16 + l15;
            blo[j] = *(const bf16x8*)&Bs[cur][r * 64 + ((slot ^ (r & 7)) << 3)];
            bhi[j] = *(const bf16x8*)&Bs[cur][r * 64 + (((slot + 4) ^ (r & 7)) << 3)];
        }
#pragma unroll
        for (int i = 0; i < MF; ++i)
#pragma unroll
            for (int j = 0; j < NF; ++j) {
                acc[i][j] = __builtin_amdgcn_mfma_f32_16x16x32_bf16(alo[i], blo[j], acc[i][j], 0, 0, 0);
                acc[i][j] = __builtin_amdgcn_mfma_f32_16x16x32_bf16(ahi[i], bhi[j], acc[i][j], 0, 0, 0);
            }
        __syncthreads();   // drains vmcnt(0): next buffer ready; reads of cur done
        cur ^= 1;
    }

    unsigned short* C16 = (unsigned short*)Cout + (long)zlo * sClo + (long)zhi * sChi;
    float*          C32 = (float*)Cout + (long)zlo * sClo + (long)zhi * sChi;
    const float* biasb = (BIAS != 0) ? bias + (long)zhi * sBiasHi : nullptr;
    const int r0 = slot << 2;
#pragma unroll
    for (int i = 0; i < MF; ++i) {
#pragma unroll
        for (int r = 0; r < 4; ++r) {
            const int m = m0 + wm + i * 16 + r0 + r;
            const float brow = (BIAS == 1) ? biasb[m] : 0.0f;
#pragma unroll
            for (int j = 0; j < NF; ++j) {
                const int n = n0 + wn + j * 16 + l15;
                const float bb = (BIAS == 2) ? biasb[n] : brow;
                const float o = alpha * (acc[i][j][r] + bb);
                if (OBF16) C16[(long)m * ldc + n] = f2bf(o);
                else       C32[(long)m * ldc + n] = o;
            }
        }
    }
}

// ---------------------------------------------------------------------------
// Fused QK^T + softmax -> Pcat bf16. QK layout: (32,1024,128), z<16 = depth
// group [Qdep|Kdep], z>=16 = rgb group [Qrgb|Krgb]; scale pre-folded into Wq.
// dir0 (rgb attends depth): Q = QK[16+b][:,0:64], K = QK[b][:,64:128].
// dir1:                     Q = QK[b][:,0:64],    K = QK[16+b][:,64:128].
// ---------------------------------------------------------------------------
__global__ __launch_bounds__(256)
void attn_fused(const unsigned short* __restrict__ QK, unsigned short* __restrict__ Pcat)
{
    __shared__ unsigned short Ss[32][1024];
    const int t = threadIdx.x, lane = t & 63, w = t >> 6;
    const int bx = blockIdx.x, b = blockIdx.y, dir = blockIdx.z;
    const unsigned short* Q = QK + (long)(dir ? b : 16 + b) * 131072;
    const unsigned short* K = QK + (long)(dir ? 16 + b : b) * 131072 + 64;
    const int l15 = lane & 15, kg = (lane >> 4) << 3;

    const long mrow = bx * 32 + (w & 1) * 16 + l15;
    bf16x8 aq0 = *(const bf16x8*)&Q[mrow * 128 + kg];
    bf16x8 aq1 = *(const bf16x8*)&Q[mrow * 128 + 32 + kg];

    const int colbase = (w >> 1) * 512;
    const int rbase = (w & 1) * 16 + (lane >> 4) * 4;
    for (int c = 0; c < 4; ++c) {
        const int n0 = colbase + c * 128;
        bf16x8 bk0[8], bk1[8];
#pragma unroll
        for (int j = 0; j < 8; ++j) {
            const long krow = n0 + j * 16 + l15;
            bk0[j] = *(const bf16x8*)&K[krow * 128 + kg];
            bk1[j] = *(const bf16x8*)&K[krow * 128 + 32 + kg];
        }
#pragma unroll
        for (int j = 0; j < 8; ++j) {
            f32x4 a = {0.f, 0.f, 0.f, 0.f};
            a = __builtin_amdgcn_mfma_f32_16x16x32_bf16(aq0, bk0[j], a, 0, 0, 0);
            a = __builtin_amdgcn_mfma_f32_16x16x32_bf16(aq1, bk1[j], a, 0, 0, 0);
            const int col = n0 + j * 16 + l15;
#pragma unroll
            for (int r = 0; r < 4; ++r)
                Ss[rbase + r][col] = f2bf(a[r]);
        }
    }
    __syncthreads();

    for (int rr = 0; rr < 8; ++rr) {
        const int R = w * 8 + rr;
        ushort8v u0 = *(const ushort8v*)&Ss[R][lane * 8];
        ushort8v u1 = *(const ushort8v*)&Ss[R][512 + lane * 8];
        float v[16];
#pragma unroll
        for (int i = 0; i < 8; ++i) { v[i] = bf2f(u0[i]); v[8 + i] = bf2f(u1[i]); }
        float m = v[0];
#pragma unroll
        for (int i = 1; i < 16; ++i) m = fmaxf(m, v[i]);
#pragma unroll
        for (int off = 32; off; off >>= 1) m = fmaxf(m, __shfl_xor(m, off));
        float s = 0.0f;
#pragma unroll
        for (int i = 0; i < 16; ++i) { v[i] = __expf(v[i] - m); s += v[i]; }
#pragma unroll
        for (int off = 32; off; off >>= 1) s += __shfl_xor(s, off);
        const float inv = 1.0f / s;
        ushort8v o0, o1;
#pragma unroll
        for (int i = 0; i < 8; ++i) { o0[i] = f2bf(v[i] * inv); o1[i] = f2bf(v[8 + i] * inv); }
        unsigned short* dst = Pcat + ((long)(b * 1024 + bx * 32 + R)) * 2048 + dir * 1024 + lane * 8;
        *(ushort8v*)dst = o0;
        *(ushort8v*)(dst + 512) = o1;
    }
}

// ---------------------------------------------------------------------------
// Transpose + fp32->bf16 for BOTH inputs in one dispatch:
//   z<16: depth -> dst0 batches; z>=16: rgb -> dst0+16MB region.
// ---------------------------------------------------------------------------
__global__ __launch_bounds__(256)
void transpose_cvt2(const float* __restrict__ src_dep, const float* __restrict__ src_rgb,
                    unsigned short* __restrict__ dst)
{
    __shared__ float tile[64][65];
    const int t = threadIdx.x;
    const int z = blockIdx.z;
    const float* s = (z < 16 ? src_dep : src_rgb) + (long)(z & 15) * 524288;
    unsigned short* d = dst + (long)z * 524288;
    const int c0 = blockIdx.x << 6, r0 = blockIdx.y << 6;
    const int lr = t >> 4, lc = (t & 15) << 2;
#pragma unroll
    for (int i = 0; i < 4; ++i) {
        f4 v = *(const f4*)(s + (long)(r0 + lr + i * 16) * HWN + c0 + lc);
        *(f4*)&tile[lr + i * 16][lc] = v;
    }
    __syncthreads();
#pragma unroll
    for (int i = 0; i < 4; ++i) {
        const int crow = lr + i * 16;
        ushort4 o;
        o.x = f2bf(tile[lc + 0][crow]);
        o.y = f2bf(tile[lc + 1][crow]);
        o.z = f2bf(tile[lc + 2][crow]);
        o.w = f2bf(tile[lc + 3][crow]);
        *(ushort4*)&d[(long)(c0 + crow) * CC + r0 + lc] = o;
    }
}

// single-tensor transpose+cvt (for the two 512x512 Wv matrices)
__global__ __launch_bounds__(256)
void transpose_cvt(const float* __restrict__ src, unsigned short* __restrict__ dst,
                   int R, int Cn)
{
    __shared__ float tile[64][65];
    const int t = threadIdx.x;
    const int c0 = blockIdx.x << 6, r0 = blockIdx.y << 6;
    const int lr = t >> 4, lc = (t & 15) << 2;
#pragma unroll
    for (int i = 0; i < 4; ++i) {
        f4 v = *(const f4*)(src + (long)(r0 + lr + i * 16) * Cn + c0 + lc);
        *(f4*)&tile[lr + i * 16][lc] = v;
    }
    __syncthreads();
#pragma unroll
    for (int i = 0; i < 4; ++i) {
        const int crow = lr + i * 16;
        ushort4 o;
        o.x = f2bf(tile[lc + 0][crow]);
        o.y = f2bf(tile[lc + 1][crow]);
        o.z = f2bf(tile[lc + 2][crow]);
        o.w = f2bf(tile[lc + 3][crow]);
        *(ushort4*)&dst[(long)(c0 + crow) * R + r0 + lc] = o;
    }
}

__global__ __launch_bounds__(256)
void cvt_flat(const float* __restrict__ src, unsigned short* __restrict__ dst, int n4)
{
    const int i = blockIdx.x * 256 + threadIdx.x;
    if (i < n4) {
        f4 v = ((const f4*)src)[i];
        ushort4 o;
        o.x = f2bf(v.x); o.y = f2bf(v.y); o.z = f2bf(v.z); o.w = f2bf(v.w);
        ((ushort4*)dst)[i] = o;
    }
}

// build Wqk (256 rows x 512): [Wq_dep*s; Wk_dep; Wq_rgb*s; Wk_rgb]
__global__ __launch_bounds__(256)
void prep_wqk(const float* __restrict__ wqd, const float* __restrict__ wkd,
              const float* __restrict__ wqr, const float* __restrict__ wkr,
              unsigned short* __restrict__ dst, float s)
{
    const int i4 = blockIdx.x * 256 + threadIdx.x;      // 0..32767 (f4 units)
    const int row = i4 >> 7;                            // 512 floats = 128 f4 per row
    const int seg = row >> 6;
    const float* src = (seg == 0) ? wqd : (seg == 1) ? wkd : (seg == 2) ? wqr : wkr;
    const float sc = (seg & 1) ? 1.0f : s;
    f4 v = ((const f4*)src)[((row & 63) << 7) + (i4 & 127)];
    ushort4 o;
    o.x = f2bf(v.x * sc); o.y = f2bf(v.y * sc); o.z = f2bf(v.z * sc); o.w = f2bf(v.w * sc);
    ((ushort4*)dst)[i4] = o;
}

// biascat (256 fp32): [bq_dep*s | bk_dep | bq_rgb*s | bk_rgb]
__global__ __launch_bounds__(256)
void prep_bias(const float* __restrict__ bqd, const float* __restrict__ bkd,
               const float* __restrict__ bqr, const float* __restrict__ bkr,
               float* __restrict__ dst, float s)
{
    const int t = threadIdx.x;
    float v;
    if (t < 64)       v = bqd[t] * s;
    else if (t < 128) v = bkd[t - 64];
    else if (t < 192) v = bqr[t - 128] * s;
    else              v = bkr[t - 192];
    dst[t] = v;
}

// bfuse[o] = sum_c Wf[o,c]*bv_dep[c] + Wf[o,512+c]*bv_rgb[c]
__global__ __launch_bounds__(256)
void bfuse_k(const float* __restrict__ Wf, const float* __restrict__ bv1,
             const float* __restrict__ bv2, float* __restrict__ bfuse)
{
    const int o = blockIdx.x, t = threadIdx.x;
    const float* row = Wf + (long)o * 1024;
    float s = row[t] * bv1[t] + row[512 + t] * bv2[t]
            + row[256 + t] * bv1[256 + t] + row[768 + t] * bv2[256 + t];
#pragma unroll
    for (int off = 32; off; off >>= 1) s += __shfl_xor(s, off);
    __shared__ float r[4];
    if ((t & 63) == 0) r[t >> 6] = s;
    __syncthreads();
    if (t == 0) bfuse[o] = r[0] + r[1] + r[2] + r[3];
}

__global__ __launch_bounds__(256)
void bn_stats(const float* __restrict__ fused, float* __restrict__ stats)
{
    const int o = blockIdx.x, t = threadIdx.x;
    float s = 0.0f, s2 = 0.0f;
    for (int b = 0; b < NB; ++b) {
        f4 v = *(const f4*)(fused + ((long)(b * CC + o) << 10) + (t << 2));
        s  += v.x + v.y + v.z + v.w;
        s2 += v.x * v.x + v.y * v.y + v.z * v.z + v.w * v.w;
    }
#pragma unroll
    for (int off = 32; off; off >>= 1) {
        s  += __shfl_xor(s, off);
        s2 += __shfl_xor(s2, off);
    }
    __shared__ float r1[4], r2[4];
    if ((t & 63) == 0) { r1[t >> 6] = s; r2[t >> 6] = s2; }
    __syncthreads();
    if (t == 0) {
        const float S1 = r1[0] + r1[1] + r1[2] + r1[3];
        const float S2 = r2[0] + r2[1] + r2[2] + r2[3];
        const float mean = S1 * (1.0f / 16384.0f);
        const float var  = S2 * (1.0f / 16384.0f) - mean * mean;
        stats[o]      = mean;
        stats[CC + o] = rsqrtf(var + 1e-5f);
    }
}

__global__ __launch_bounds__(256)
void bn_apply(const float* __restrict__ fused, const float* __restrict__ stats,
              const float* __restrict__ gamma, const float* __restrict__ beta,
              float* __restrict__ out)
{
    const long i4 = (long)blockIdx.x * 256 + threadIdx.x;
    f4 v = ((const f4*)fused)[i4];
    const int o = (int)((i4 >> 8) & 511);
    const float is = stats[CC + o];
    const float g  = gamma[o] * is;
    const float bb = beta[o] - stats[o] * g;
    v.x = fmaxf(fmaf(v.x, g, bb), 0.0f);
    v.y = fmaxf(fmaf(v.y, g, bb), 0.0f);
    v.z = fmaxf(fmaf(v.z, g, bb), 0.0f);
    v.w = fmaxf(fmaf(v.w, g, bb), 0.0f);
    ((f4*)out)[i4] = v;
}

// ---------------------------------------------------------------------------
// Workspace layout (BYTE offsets). depT FIRST, rgbT adjacent (proj/Acat span
// z 0..31 across both with a single batch stride). Total ~180 MB.
// ---------------------------------------------------------------------------
static constexpr long B_depT  = 0;          // bf16 (16,1024,512)
static constexpr long B_rgbT  = 16777216;   // bf16 (16,1024,512)
static constexpr long B_WvT1  = 33554432;   // bf16 512x512 (Wv_dep^T)
static constexpr long B_WvT2  = 34078720;   // adjacent
static constexpr long B_Wfb   = 34603008;   // bf16 512x1024
static constexpr long B_Wqk   = 35651584;   // bf16 256x512
static constexpr long B_Wc1   = 35913728;   // bf16 512x512 (Wf1@Wv_dep)
static constexpr long B_Wc2   = 36438016;   // adjacent
static constexpr long B_bfu   = 36962304;   // fp32 512
static constexpr long B_bias  = 36964352;   // fp32 256
static constexpr long B_QK    = 36966400;   // bf16 (32,1024,128)
static constexpr long B_Acat  = 45355008;   // bf16 (16,512,2048)
static constexpr long B_Pcat  = 78909440;   // bf16 (16,1024,2048)
static constexpr long B_fused = 146018304;  // fp32 (16,512,1024)
static constexpr long B_stats = 179572736;  // fp32 1024

extern "C" void kernel_launch(void* const* d_in, const int* in_sizes, int n_in,
                              void* d_out, int out_size, void* d_ws, size_t ws_size,
                              hipStream_t stream)
{
    const float* rgb    = (const float*)d_in[0];
    const float* depth  = (const float*)d_in[1];
    const float* Wq_rgb = (const float*)d_in[2];
    const float* bq_rgb = (const float*)d_in[3];
    const float* Wk_dep = (const float*)d_in[4];
    const float* bk_dep = (const float*)d_in[5];
    const float* Wv_dep = (const float*)d_in[6];
    const float* bv_dep = (const float*)d_in[7];
    const float* Wq_dep = (const float*)d_in[8];
    const float* bq_dep = (const float*)d_in[9];
    const float* Wk_rgb = (const float*)d_in[10];
    const float* bk_rgb = (const float*)d_in[11];
    const float* Wv_rgb = (const float*)d_in[12];
    const float* bv_rgb = (const float*)d_in[13];
    const float* W_fuse = (const float*)d_in[14];
    const float* gamma  = (const float*)d_in[15];
    const float* beta   = (const float*)d_in[16];
    char* ws = (char*)d_ws;
    float* out = (float*)d_out;

    const float inv_scale = 0.044194173824159223f;  // 1/sqrt(512)
    dim3 blk(256);

    unsigned short* depT = (unsigned short*)(ws + B_depT);   // rgbT = depT + 16*524288
    unsigned short* WvT1 = (unsigned short*)(ws + B_WvT1);
    unsigned short* WvT2 = (unsigned short*)(ws + B_WvT2);
    unsigned short* Wfb  = (unsigned short*)(ws + B_Wfb);
    unsigned short* Wqk  = (unsigned short*)(ws + B_Wqk);
    unsigned short* Wc1  = (unsigned short*)(ws + B_Wc1);
    float*          bfu  = (float*)(ws + B_bfu);
    float*          bias = (float*)(ws + B_bias);
    unsigned short* QK   = (unsigned short*)(ws + B_QK);
    unsigned short* Acat = (unsigned short*)(ws + B_Acat);
    unsigned short* Pcat = (unsigned short*)(ws + B_Pcat);
    float*          fused= (float*)(ws + B_fused);
    float*          stats= (float*)(ws + B_stats);

    // --- prep: conversions ---
    transpose_cvt2<<<dim3(16, 8, 32), blk, 0, stream>>>(depth, rgb, depT);
    transpose_cvt<<<dim3(8, 8, 1), blk, 0, stream>>>(Wv_dep, WvT1, CC, CC);
    transpose_cvt<<<dim3(8, 8, 1), blk, 0, stream>>>(Wv_rgb, WvT2, CC, CC);
    cvt_flat<<<512, blk, 0, stream>>>(W_fuse, Wfb, 131072);
    prep_wqk<<<128, blk, 0, stream>>>(Wq_dep, Wk_dep, Wq_rgb, Wk_rgb, Wqk, inv_scale);
    prep_bias<<<1, blk, 0, stream>>>(bq_dep, bk_dep, bq_rgb, bk_rgb, bias, inv_scale);
    bfuse_k<<<512, blk, 0, stream>>>(W_fuse, bv_dep, bv_rgb, bfu);

    // --- Wc pair (z=0: Wf[:,:512]@Wv_dep -> Wc1; z=1: Wf[:,512:]@Wv_rgb -> Wc2) ---
    mfma_g<128, 128, 0, true, 0><<<dim3(4, 4, 2), blk, 0, stream>>>(
        Wfb, 0, 512, 1024, WvT1, 0, 262144, 512, nullptr, 0,
        Wc1, 0, 262144, 512, 512, 1.0f);

    // --- projections: QK[z] = X[z] @ Wqk[group]^T + biascat[group]
    //     z<16: depth -> [Qdep|Kdep]; z>=16: rgb -> [Qrgb|Krgb]. Scale in Wq. ---
    mfma_g<128, 64, 2, true, 4><<<dim3(2, 8, 32), blk, 0, stream>>>(
        depT, 524288, 8388608, 512, Wqk, 0, 65536, 512, bias, 128,
        QK, 131072, 2097152, 128, 512, 1.0f);

    // --- Acat: z<16: Wc1@depth -> cols 0:1024; z>=16: Wc2@rgb -> cols 1024:2048 ---
    mfma_g<128, 128, 0, true, 4><<<dim3(8, 4, 32), blk, 0, stream>>>(
        Wc1, 0, 262144, 512, depT, 524288, 8388608, 512, nullptr, 0,
        Acat, 1048576, 1024, 2048, 512, 1.0f);

    // --- fused attention: QK^T + softmax -> Pcat (both dirs) ---
    attn_fused<<<dim3(32, NB, 2), blk, 0, stream>>>(QK, Pcat);

    // --- fused = Acat @ Pcat^T + bfuse (K=2048) ---
    mfma_g<128, 128, 1, false, 4><<<dim3(8, 4, 16), blk, 0, stream>>>(
        Acat, 1048576, 0, 2048, Pcat, 2097152, 0, 2048, bfu, 0,
        fused, 524288, 0, 1024, 2048, 1.0f);

    // --- BN (training stats) + ReLU ---
    bn_stats<<<CC, blk, 0, stream>>>(fused, stats);
    bn_apply<<<8192, blk, 0, stream>>>(fused, stats, gamma, beta, out);
}